// Round 4
// baseline (511.987 us; speedup 1.0000x reference)
//
#include <hip/hip_runtime.h>

// Problem constants (B=4, V=1024, L=2048, H=2048, TEMP=1, EPS=1e-12)
#define H_ 2048

typedef __attribute__((ext_vector_type(8))) short short8;
typedef __attribute__((ext_vector_type(4))) float f32x4;
typedef __attribute__((ext_vector_type(4))) unsigned int u32x4;

__device__ __forceinline__ unsigned short f2bf(float f) {
  unsigned int u = __builtin_bit_cast(unsigned int, f);
  u += 0x7FFFu + ((u >> 16) & 1u);  // RTNE
  return (unsigned short)(u >> 16);
}
__device__ __forceinline__ float bf2f(unsigned short h) {
  unsigned int u = ((unsigned int)h) << 16;
  return __builtin_bit_cast(float, u);
}
__device__ __forceinline__ unsigned int pk2(float a, float b) {
  return (unsigned int)f2bf(a) | ((unsigned int)f2bf(b) << 16);
}

#define GLDS16(gp, lp)                                                 \
  __builtin_amdgcn_global_load_lds(                                    \
      (const __attribute__((address_space(1))) void*)(gp),             \
      (__attribute__((address_space(3))) void*)(lp), 16, 0, 0)

// ---------------------------------------------------------------------------
// prep: per-row 1/max(||row||,eps) + raw bf16 copy; rows >= validRows -> zeros
// ---------------------------------------------------------------------------
__global__ __launch_bounds__(256) void prep_rows(
    const float* __restrict__ in, long sIn,
    unsigned short* __restrict__ outBf, long sOut,
    float* __restrict__ rnorm, int validRows) {
  const int tid = threadIdx.x;
  const int r = blockIdx.x, b = blockIdx.y;
  unsigned short* orow = outBf + (long)b * sOut + (long)r * H_ + tid * 8;
  if (r >= validRows) {
    *(u32x4*)orow = (u32x4){0u, 0u, 0u, 0u};
    if (tid == 0) rnorm[b * H_ + r] = 0.f;
    return;
  }
  const float* row = in + (long)b * sIn + (long)r * H_ + tid * 8;
  f32x4 x0 = *(const f32x4*)row;
  f32x4 x1 = *(const f32x4*)(row + 4);
  float ss = x0[0]*x0[0] + x0[1]*x0[1] + x0[2]*x0[2] + x0[3]*x0[3]
           + x1[0]*x1[0] + x1[1]*x1[1] + x1[2]*x1[2] + x1[3]*x1[3];
#pragma unroll
  for (int o = 32; o; o >>= 1) ss += __shfl_xor(ss, o, 64);
  __shared__ float red[4];
  if ((tid & 63) == 0) red[tid >> 6] = ss;
  __syncthreads();
  if (tid == 0) {
    float tot = red[0] + red[1] + red[2] + red[3];
    rnorm[b * H_ + r] = 1.f / fmaxf(sqrtf(tot), 1e-12f);
  }
  u32x4 o;
  o[0] = pk2(x0[0], x0[1]); o[1] = pk2(x0[2], x0[3]);
  o[2] = pk2(x1[0], x1[1]); o[3] = pk2(x1[2], x1[3]);
  *(u32x4*)orow = o;
}

// ---------------------------------------------------------------------------
// column sums (means over padded length 2048) — two stage for parallelism
// ---------------------------------------------------------------------------
__global__ __launch_bounds__(256) void col_sum_part(
    const float* __restrict__ vis, const float* __restrict__ lang,
    float* __restrict__ part) {
  const int h = blockIdx.x * 256 + threadIdx.x;
  const int y = blockIdx.y;
  const int which = blockIdx.z & 1;
  const int b = blockIdx.z >> 1;
  const int rows = which ? 2048 : 1024;
  const int r0 = y * 256;
  float s = 0.f;
  if (r0 < rows) {
    const float* p = (which ? lang + (long)b * (2048L * 2048)
                            : vis + (long)b * (1024L * 2048)) + (long)r0 * H_ + h;
#pragma unroll 4
    for (int i = 0; i < 256; ++i) s += p[(long)i * H_];
  }
  part[(((long)which * 4 + b) * 8 + y) * H_ + h] = s;
}

__global__ __launch_bounds__(256) void col_sum_final(
    const float* __restrict__ part, float* __restrict__ vavg,
    float* __restrict__ lavg) {
  const int h = blockIdx.x * 256 + threadIdx.x;
  const int b = blockIdx.y;
  const int which = blockIdx.z;
  const float* p = part + (((long)which * 4 + b) * 8) * H_ + h;
  float s = 0.f;
#pragma unroll
  for (int y = 0; y < 8; ++y) s += p[y * H_];
  (which ? lavg : vavg)[b * H_ + h] = s * (1.f / 2048.f);
}

// ---------------------------------------------------------------------------
// bias GEMV: bias[b,h] = sum_{d<2048} avg[b,d] * W[h*4096 + d]
// ---------------------------------------------------------------------------
__global__ __launch_bounds__(256) void bias_gemv(
    const float* __restrict__ W, const float* __restrict__ avg,
    float* __restrict__ bias) {
  const int lane = threadIdx.x & 63;
  const int wv = threadIdx.x >> 6;
  const int h = blockIdx.x * 4 + wv;
  const float* wrow = W + (long)h * 4096;
  float a0 = 0.f, a1 = 0.f, a2 = 0.f, a3 = 0.f;
#pragma unroll
  for (int i = 0; i < 8; ++i) {
    const int d = i * 256 + lane * 4;
    f32x4 w4 = *(const f32x4*)(wrow + d);
    f32x4 v0 = *(const f32x4*)(avg + 0 * H_ + d);
    f32x4 v1 = *(const f32x4*)(avg + 1 * H_ + d);
    f32x4 v2 = *(const f32x4*)(avg + 2 * H_ + d);
    f32x4 v3 = *(const f32x4*)(avg + 3 * H_ + d);
    a0 += w4[0]*v0[0] + w4[1]*v0[1] + w4[2]*v0[2] + w4[3]*v0[3];
    a1 += w4[0]*v1[0] + w4[1]*v1[1] + w4[2]*v1[2] + w4[3]*v1[3];
    a2 += w4[0]*v2[0] + w4[1]*v2[1] + w4[2]*v2[2] + w4[3]*v2[3];
    a3 += w4[0]*v3[0] + w4[1]*v3[1] + w4[2]*v3[2] + w4[3]*v3[3];
  }
#pragma unroll
  for (int o = 32; o; o >>= 1) {
    a0 += __shfl_xor(a0, o, 64);
    a1 += __shfl_xor(a1, o, 64);
    a2 += __shfl_xor(a2, o, 64);
    a3 += __shfl_xor(a3, o, 64);
  }
  if (lane == 0) {
    bias[0 * H_ + h] = a0; bias[1 * H_ + h] = a1;
    bias[2 * H_ + h] = a2; bias[3 * H_ + h] = a3;
  }
}

// ---------------------------------------------------------------------------
// transpose lang (f32 [b][l][h]) -> lang_T (bf16 [b][h][l])
// ---------------------------------------------------------------------------
__global__ __launch_bounds__(256) void transpose_bf(
    const float* __restrict__ in, unsigned short* __restrict__ out) {
  __shared__ unsigned short tle[64][72];
  const int b = blockIdx.z;
  const int l0 = blockIdx.y * 64, h0 = blockIdx.x * 64;
  const float* inb = in + (long)b * (2048L * 2048);
  unsigned short* outb = out + (long)b * (2048L * 2048);
#pragma unroll
  for (int i = 0; i < 16; ++i) {
    const int idx = i * 256 + threadIdx.x;
    const int r = idx >> 6, c = idx & 63;
    tle[r][c] = f2bf(inb[(long)(l0 + r) * H_ + h0 + c]);
  }
  __syncthreads();
#pragma unroll
  for (int i = 0; i < 16; ++i) {
    const int idx = i * 256 + threadIdx.x;
    const int r = idx >> 6, c = idx & 63;  // r = h-local, c = l-local
    outb[(long)(h0 + r) * H_ + l0 + c] = tle[c][r];
  }
}

// ---------------------------------------------------------------------------
// extract W[:, 2048:4096] as bf16 row-major [h][k]
// ---------------------------------------------------------------------------
__global__ __launch_bounds__(256) void extract_whi(
    const float* __restrict__ Wvl, const float* __restrict__ Wlv,
    unsigned short* __restrict__ WvlHi, unsigned short* __restrict__ WlvHi) {
  const int h = blockIdx.x;
  const int which = blockIdx.y;
  const float* src = (which ? Wlv : Wvl) + (long)h * 4096 + 2048 + threadIdx.x * 8;
  unsigned short* dst = (which ? WlvHi : WvlHi) + (long)h * H_ + threadIdx.x * 8;
  f32x4 x0 = *(const f32x4*)src;
  f32x4 x1 = *(const f32x4*)(src + 4);
  u32x4 o;
  o[0] = pk2(x0[0], x0[1]); o[1] = pk2(x0[2], x0[3]);
  o[2] = pk2(x1[0], x1[1]); o[3] = pk2(x1[2], x1[3]);
  *(u32x4*)dst = o;
}

// ---------------------------------------------------------------------------
// row softmax in place over bf16 [rows][2048]
// ---------------------------------------------------------------------------
__global__ __launch_bounds__(256) void softmax_rows(unsigned short* __restrict__ S) {
  const int tid = threadIdx.x;
  const int lane = tid & 63, wv = tid >> 6;
  unsigned short* rowp = S + (long)blockIdx.x * H_ + tid * 8;
  u32x4 raw = *(const u32x4*)rowp;
  float v[8];
#pragma unroll
  for (int i = 0; i < 4; ++i) {
    v[2 * i]     = bf2f((unsigned short)(raw[i] & 0xFFFFu));
    v[2 * i + 1] = bf2f((unsigned short)(raw[i] >> 16));
  }
  float mx = v[0];
#pragma unroll
  for (int i = 1; i < 8; ++i) mx = fmaxf(mx, v[i]);
#pragma unroll
  for (int o = 32; o; o >>= 1) mx = fmaxf(mx, __shfl_xor(mx, o, 64));
  __shared__ float red[4];
  if (lane == 0) red[wv] = mx;
  __syncthreads();
  const float MX = fmaxf(fmaxf(red[0], red[1]), fmaxf(red[2], red[3]));
  float p[8], s = 0.f;
#pragma unroll
  for (int i = 0; i < 8; ++i) { p[i] = __expf(v[i] - MX); s += p[i]; }
#pragma unroll
  for (int o = 32; o; o >>= 1) s += __shfl_xor(s, o, 64);
  __syncthreads();
  if (lane == 0) red[wv] = s;
  __syncthreads();
  const float inv = 1.f / (red[0] + red[1] + red[2] + red[3]);
  u32x4 o;
#pragma unroll
  for (int i = 0; i < 4; ++i) o[i] = pk2(p[2 * i] * inv, p[2 * i + 1] * inv);
  *(u32x4*)rowp = o;
}

// ---------------------------------------------------------------------------
// NT GEMM (C = A * B^T), 256x256 tile, BK=64, 8 waves (2M x 4N), 8-phase
// schedule (T3+T4+T5), double-buffered 128KB LDS, counted vmcnt(8),
// XOR LDS swizzle g' = g ^ (row&7) via inverse-swizzled global source.
// R3 change: fragment LDS reads are OPAQUE inline-asm ds_read_b128 so the
// compiler cannot insert vmcnt(0) drains to order them against the
// (may-aliasing) global_load_lds writes; ordering is enforced manually by
// the counted-vmcnt ledger + barriers, with explicit lgkmcnt(0) +
// sched_barrier(0) before each MFMA cluster (rule #18).
// ---------------------------------------------------------------------------
struct EpArgs {
  unsigned short* Sout; const float* rv; const float* rl;  // MODE 0
  float* Fout;                                             // MODE 1
  const float* resid; const float* fusedIn; const float* bias; float* Oout;
  long sResid, sFused, sOut;                               // MODE 2
};

#define BAR_ asm volatile("s_barrier" ::: "memory")
#define WAITV_(n) asm volatile("s_waitcnt vmcnt(" #n ")" ::: "memory")
#define SYNCL_                                        \
  do {                                                \
    asm volatile("s_waitcnt lgkmcnt(0)" ::: "memory");\
    __builtin_amdgcn_sched_barrier(0);                \
  } while (0)

template <int MODE>
__global__ __launch_bounds__(512, 2) void gemm_nt(
    const unsigned short* __restrict__ A, long sA,
    const unsigned short* __restrict__ B, long sB, EpArgs ep) {
  // LDS: A buf0 [0,16384) | A buf1 [16384,32768) | B buf0 | B buf1 (elems)
  __shared__ unsigned short LDS[65536];  // 128 KB

  const int tid = threadIdx.x;
  const int lane = tid & 63;
  const int wave = tid >> 6;

  // XCD-aware bijective block swizzle (nwg % 8 == 0 for all our grids)
  const int gx = gridDim.x, gy = gridDim.y;
  const int nwg = gx * gy * gridDim.z;
  const int lin = blockIdx.x + gx * (blockIdx.y + gy * blockIdx.z);
  const int swz = (lin & 7) * (nwg >> 3) + (lin >> 3);
  const int bx = swz % gx;
  const int rest = swz / gx;
  const int by = rest % gy;
  const int b = rest / gy;
  const int bm = by << 8;
  const int bn = bx << 8;

  const unsigned short* Ab = A + (long)b * sA;
  const unsigned short* Bb = B + (long)b * sB;

  // --- staging addressing (global_load_lds: linear dest, pre-swz source) ---
  const int srow = tid >> 3;                              // 0..63
  const int colOff = ((tid & 7) ^ (srow & 7)) << 3;       // swizzled k-offset
  const unsigned short* gA0 = Ab + (long)(bm + srow) * H_ + colOff;
  const unsigned short* gA1 = gA0 + 128 * H_;
  const unsigned short* gB0 = Bb + (long)(bn + srow) * H_ + colOff;
  const unsigned short* gB1 = gB0 + 128 * H_;
  const int ldst = wave * 512;  // wave-uniform LDS base (HW adds lane*16B)

#define STAGE_A_(kt, bo)                                          \
  do {                                                            \
    const unsigned short* pa0_ = gA0 + (kt) * 64;                 \
    const unsigned short* pa1_ = gA1 + (kt) * 64;                 \
    GLDS16(pa0_,           &LDS[(bo) + ldst]);                    \
    GLDS16(pa0_ + 64 * H_, &LDS[(bo) + 4096 + ldst]);             \
    GLDS16(pa1_,           &LDS[(bo) + 8192 + ldst]);             \
    GLDS16(pa1_ + 64 * H_, &LDS[(bo) + 12288 + ldst]);            \
  } while (0)
#define STAGE_B_(kt, bo)                                          \
  do {                                                            \
    const unsigned short* pb0_ = gB0 + (kt) * 64;                 \
    const unsigned short* pb1_ = gB1 + (kt) * 64;                 \
    GLDS16(pb0_,           &LDS[(bo) + ldst]);                    \
    GLDS16(pb0_ + 64 * H_, &LDS[(bo) + 4096 + ldst]);             \
    GLDS16(pb1_,           &LDS[(bo) + 8192 + ldst]);             \
    GLDS16(pb1_ + 64 * H_, &LDS[(bo) + 12288 + ldst]);            \
  } while (0)

  // --- fragment addressing (swizzled read, byte offsets via AS3 ptrtoint) ---
  const int row16 = lane & 15;
  const int kg = lane >> 4;
  const int wr = (wave >> 2) << 7;   // 0 or 128
  const int wc = (wave & 3) << 6;    // 0,64,128,192
  const int sw0 = (kg ^ (row16 & 7)) << 3;
  const int sw1 = ((4 + kg) ^ (row16 & 7)) << 3;
  const int ra = (wr + row16) << 6;
  const int rb = (wc + row16) << 6;

#define LDSO_(idx)                                                        \
  ((unsigned)(unsigned long long)(__attribute__((address_space(3)))       \
                                      const void*)&LDS[idx])
#define DSR_(dst, idx) \
  asm volatile("ds_read_b128 %0, %1" : "=v"(dst) : "v"(LDSO_(idx)))

  f32x4 acc[8][4];
#pragma unroll
  for (int m = 0; m < 8; ++m)
#pragma unroll
    for (int n = 0; n < 4; ++n) acc[m][n] = (f32x4){0.f, 0.f, 0.f, 0.f};
  short8 aF[8][2], bF[4][2];

#define RD4A_(MLO)                                                    \
  do {                                                                \
    _Pragma("unroll") for (int m_ = 0; m_ < 4; ++m_) {                \
      DSR_(aF[(MLO) + m_][0], bufA + ra + ((MLO) + m_) * 1024 + sw0); \
      DSR_(aF[(MLO) + m_][1], bufA + ra + ((MLO) + m_) * 1024 + sw1); \
    }                                                                 \
  } while (0)
#define RD2B_(NLO)                                                    \
  do {                                                                \
    _Pragma("unroll") for (int n_ = 0; n_ < 2; ++n_) {                \
      DSR_(bF[(NLO) + n_][0], bufB + rb + ((NLO) + n_) * 1024 + sw0); \
      DSR_(bF[(NLO) + n_][1], bufB + rb + ((NLO) + n_) * 1024 + sw1); \
    }                                                                 \
  } while (0)

#define MF16_(MLO, NLO)                                                      \
  do {                                                                       \
    __builtin_amdgcn_s_setprio(1);                                           \
    _Pragma("unroll") for (int m_ = 0; m_ < 4; ++m_)                         \
    _Pragma("unroll") for (int n_ = 0; n_ < 2; ++n_) {                       \
      acc[(MLO) + m_][(NLO) + n_] = __builtin_amdgcn_mfma_f32_16x16x32_bf16( \
          aF[(MLO) + m_][0], bF[(NLO) + n_][0],                              \
          acc[(MLO) + m_][(NLO) + n_], 0, 0, 0);                             \
      acc[(MLO) + m_][(NLO) + n_] = __builtin_amdgcn_mfma_f32_16x16x32_bf16( \
          aF[(MLO) + m_][1], bF[(NLO) + n_][1],                              \
          acc[(MLO) + m_][(NLO) + n_], 0, 0, 0);                             \
    }                                                                        \
    __builtin_amdgcn_s_setprio(0);                                           \
  } while (0)

#define ITER_(t, DOSTAGE, WV)                                               \
  do {                                                                      \
    const int bufA = ((t) & 1) << 14;                                       \
    const int bufB = 32768 + (((t) & 1) << 14);                             \
    /* p0: read A m0-3 + B n0-1, quad(0,0) */                               \
    RD4A_(0); RD2B_(0);                                                     \
    BAR_; SYNCL_; MF16_(0, 0); BAR_;                                        \
    /* p1: read A m4-7, quad(1,0) */                                        \
    RD4A_(4);                                                               \
    BAR_; SYNCL_; MF16_(4, 0); BAR_;                                        \
    /* p2: read B n2-3, stage A(t+2), quad(0,1) */                          \
    RD2B_(2);                                                               \
    if (DOSTAGE) STAGE_A_((t) + 2, bufA);                                   \
    BAR_; SYNCL_; MF16_(0, 2); BAR_;                                        \
    /* p3: stage B(t+2), counted wait, quad(1,1) */                         \
    if (DOSTAGE) STAGE_B_((t) + 2, bufB);                                   \
    WV; BAR_; MF16_(4, 2); BAR_;                                            \
  } while (0)

  // prologue: tiles 0 (buf0) and 1 (buf1); wait tile 0 landed (8 newest = t1)
  STAGE_A_(0, 0); STAGE_B_(0, 32768);
  STAGE_A_(1, 16384); STAGE_B_(1, 32768 + 16384);
  WAITV_(8);
  BAR_;

  for (int t = 0; t < 30; ++t) { ITER_(t, 1, WAITV_(8)); }
  ITER_(30, 0, WAITV_(0));
  ITER_(31, 0, (void)0);

  // C/D layout: col = lane&15, row = (lane>>4)*4 + j   [verified m89/m91]
  const int cr0 = bm + wr + kg * 4;
  const int cc0 = bn + wc + row16;

  if (MODE == 0) {
    float rvv[8][4], rlv[4];
#pragma unroll
    for (int m = 0; m < 8; ++m)
#pragma unroll
      for (int j = 0; j < 4; ++j) rvv[m][j] = ep.rv[b * H_ + cr0 + m * 16 + j];
#pragma unroll
    for (int n = 0; n < 4; ++n) rlv[n] = ep.rl[b * H_ + cc0 + n * 16];
    unsigned short* Sb = ep.Sout + (long)b * (H_ * (long)H_);
#pragma unroll
    for (int m = 0; m < 8; ++m)
#pragma unroll
      for (int n = 0; n < 4; ++n)
#pragma unroll
        for (int j = 0; j < 4; ++j) {
          const long idx = (long)(cr0 + m * 16 + j) * H_ + cc0 + n * 16;
          Sb[idx] = f2bf(acc[m][n][j] * rvv[m][j] * rlv[n]);
        }
  } else if (MODE == 1) {
    float* Fb = ep.Fout + (long)b * (H_ * (long)H_);
#pragma unroll
    for (int m = 0; m < 8; ++m)
#pragma unroll
      for (int n = 0; n < 4; ++n)
#pragma unroll
        for (int j = 0; j < 4; ++j) {
          const long idx = (long)(cr0 + m * 16 + j) * H_ + cc0 + n * 16;
          Fb[idx] = acc[m][n][j];
        }
  } else {
    const float* Rb = ep.resid + (long)b * ep.sResid;
    const float* Fb = ep.fusedIn + (long)b * ep.sFused;
    float* Ob = ep.Oout + (long)b * ep.sOut;
    float bv[4];
#pragma unroll
    for (int n = 0; n < 4; ++n) bv[n] = ep.bias[b * H_ + cc0 + n * 16];
#pragma unroll
    for (int m = 0; m < 8; ++m)
#pragma unroll
      for (int n = 0; n < 4; ++n)
#pragma unroll
        for (int j = 0; j < 4; ++j) {
          const long idx = (long)(cr0 + m * 16 + j) * H_ + cc0 + n * 16;
          const float x = acc[m][n][j] + bv[n];
          const float g = 1.f / (1.f + __expf(-x));
          Ob[idx] = Rb[idx] + Fb[idx] * g;
        }
  }
#undef STAGE_A_
#undef STAGE_B_
#undef RD4A_
#undef RD2B_
#undef DSR_
#undef LDSO_
#undef MF16_
#undef ITER_
}

// ---------------------------------------------------------------------------
extern "C" void kernel_launch(void* const* d_in, const int* in_sizes, int n_in,
                              void* d_out, int out_size, void* d_ws,
                              size_t ws_size, hipStream_t stream) {
  (void)in_sizes; (void)n_in; (void)out_size; (void)ws_size;
  const float* vis = (const float*)d_in[0];   // [4,1024,2048]
  const float* lang = (const float*)d_in[1];  // [4,2048,2048]
  const float* Wvl = (const float*)d_in[2];   // [2048,4096]
  const float* Wlv = (const float*)d_in[3];   // [2048,4096]

  // d_out regions: fused | vision_output | language_output
  float* out = (float*)d_out;
  float* fused = out;                      // 16,777,216 f32
  float* vis_out = out + 16777216;         //  8,388,608 f32
  float* lang_out = out + 25165824;        // 16,777,216 f32
  // scratch reuse of not-yet-final output regions:
  unsigned short* S = (unsigned short*)lang_out;     // scores/P bf16
  unsigned short* langT = (unsigned short*)vis_out;  // lang^T bf16

  // workspace layout
  char* w = (char*)d_ws;
  unsigned short* vis_bf = (unsigned short*)w;               // [4,2048,2048] bf16 (padded)
  unsigned short* lang_bf = (unsigned short*)(w + 33554432); // [4,2048,2048] bf16
  unsigned short* WvlHi = (unsigned short*)(w + 67108864);   // [2048,2048] bf16
  unsigned short* WlvHi = (unsigned short*)(w + 75497472);   // [2048,2048] bf16
  float* rv      = (float*)(w + 83886080);
  float* rl      = (float*)(w + 83918848);
  float* vavg    = (float*)(w + 83951616);
  float* lavg    = (float*)(w + 83984384);
  float* bias_vl = (float*)(w + 84017152);
  float* bias_lv = (float*)(w + 84049920);
  float* part    = (float*)(w + 84082688);  // 512KB partial col sums

  const long sV = 1024L * 2048, sL = 2048L * 2048, sP = 2048L * 2048;

  prep_rows<<<dim3(2048, 4), 256, 0, stream>>>(vis, sV, vis_bf, sP, rv, 1024);
  prep_rows<<<dim3(2048, 4), 256, 0, stream>>>(lang, sL, lang_bf, sP, rl, 2048);
  col_sum_part<<<dim3(8, 8, 8), 256, 0, stream>>>(vis, lang, part);
  col_sum_final<<<dim3(8, 4, 2), 256, 0, stream>>>(part, vavg, lavg);
  bias_gemv<<<512, 256, 0, stream>>>(Wvl, vavg, bias_vl);
  bias_gemv<<<512, 256, 0, stream>>>(Wlv, lavg, bias_lv);
  transpose_bf<<<dim3(32, 32, 4), 256, 0, stream>>>(lang, langT);
  extract_whi<<<dim3(2048, 2), 256, 0, stream>>>(Wvl, Wlv, WvlHi, WlvHi);

  // GEMM1: scores S[b,v,l] = (vis . lang) * rv * rl  -> bf16
  EpArgs e1 = {};
  e1.Sout = S; e1.rv = rv; e1.rl = rl;
  gemm_nt<0><<<dim3(8, 8, 4), 512, 0, stream>>>(vis_bf, sP, lang_bf, sP, e1);

  softmax_rows<<<8192, 256, 0, stream>>>(S);

  // GEMM2: fused[b,v,h] = P . lang  (B = lang^T, NT form) -> f32
  EpArgs e2 = {};
  e2.Fout = fused;
  gemm_nt<1><<<dim3(8, 8, 4), 512, 0, stream>>>(S, sP, langT, sP, e2);

  // GEMM3: language_output = lang + fused * sigmoid(lang.WvlHi^T + bias_vl)
  EpArgs e3 = {};
  e3.resid = lang; e3.sResid = sL;
  e3.fusedIn = fused; e3.sFused = sP;
  e3.bias = bias_vl; e3.Oout = lang_out; e3.sOut = sL;
  gemm_nt<2><<<dim3(8, 8, 4), 512, 0, stream>>>(lang_bf, sP, WvlHi, 0L, e3);

  // GEMM4: vision_output = vis + fused[:, :1024] * sigmoid(vis.WlvHi^T + bias_lv)
  EpArgs e4 = {};
  e4.resid = vis; e4.sResid = sV;
  e4.fusedIn = fused; e4.sFused = sP;
  e4.bias = bias_lv; e4.Oout = vis_out; e4.sOut = sV;
  gemm_nt<2><<<dim3(8, 4, 4), 512, 0, stream>>>(vis_bf, sP, WlvHi, 0L, e4);
}

// Round 5
// 510.108 us; speedup vs baseline: 1.0037x; 1.0037x over previous
//
#include <hip/hip_runtime.h>

// Problem constants (B=4, V=1024, L=2048, H=2048, TEMP=1, EPS=1e-12)
#define H_ 2048

typedef __attribute__((ext_vector_type(8))) short short8;
typedef __attribute__((ext_vector_type(4))) float f32x4;
typedef __attribute__((ext_vector_type(4))) unsigned int u32x4;

__device__ __forceinline__ unsigned short f2bf(float f) {
  unsigned int u = __builtin_bit_cast(unsigned int, f);
  u += 0x7FFFu + ((u >> 16) & 1u);  // RTNE
  return (unsigned short)(u >> 16);
}
__device__ __forceinline__ float bf2f(unsigned short h) {
  unsigned int u = ((unsigned int)h) << 16;
  return __builtin_bit_cast(float, u);
}
__device__ __forceinline__ unsigned int pk2(float a, float b) {
  return (unsigned int)f2bf(a) | ((unsigned int)f2bf(b) << 16);
}

#define GLDS16(gp, lp)                                                 \
  __builtin_amdgcn_global_load_lds(                                    \
      (const __attribute__((address_space(1))) void*)(gp),             \
      (__attribute__((address_space(3))) void*)(lp), 16, 0, 0)

// ---------------------------------------------------------------------------
// prep: per-row 1/max(||row||,eps) + raw bf16 copy; rows >= validRows -> zeros
// ---------------------------------------------------------------------------
__global__ __launch_bounds__(256) void prep_rows(
    const float* __restrict__ in, long sIn,
    unsigned short* __restrict__ outBf, long sOut,
    float* __restrict__ rnorm, int validRows) {
  const int tid = threadIdx.x;
  const int r = blockIdx.x, b = blockIdx.y;
  unsigned short* orow = outBf + (long)b * sOut + (long)r * H_ + tid * 8;
  if (r >= validRows) {
    *(u32x4*)orow = (u32x4){0u, 0u, 0u, 0u};
    if (tid == 0) rnorm[b * H_ + r] = 0.f;
    return;
  }
  const float* row = in + (long)b * sIn + (long)r * H_ + tid * 8;
  f32x4 x0 = *(const f32x4*)row;
  f32x4 x1 = *(const f32x4*)(row + 4);
  float ss = x0[0]*x0[0] + x0[1]*x0[1] + x0[2]*x0[2] + x0[3]*x0[3]
           + x1[0]*x1[0] + x1[1]*x1[1] + x1[2]*x1[2] + x1[3]*x1[3];
#pragma unroll
  for (int o = 32; o; o >>= 1) ss += __shfl_xor(ss, o, 64);
  __shared__ float red[4];
  if ((tid & 63) == 0) red[tid >> 6] = ss;
  __syncthreads();
  if (tid == 0) {
    float tot = red[0] + red[1] + red[2] + red[3];
    rnorm[b * H_ + r] = 1.f / fmaxf(sqrtf(tot), 1e-12f);
  }
  u32x4 o;
  o[0] = pk2(x0[0], x0[1]); o[1] = pk2(x0[2], x0[3]);
  o[2] = pk2(x1[0], x1[1]); o[3] = pk2(x1[2], x1[3]);
  *(u32x4*)orow = o;
}

// ---------------------------------------------------------------------------
// column sums (means over padded length 2048) — two stage for parallelism
// ---------------------------------------------------------------------------
__global__ __launch_bounds__(256) void col_sum_part(
    const float* __restrict__ vis, const float* __restrict__ lang,
    float* __restrict__ part) {
  const int h = blockIdx.x * 256 + threadIdx.x;
  const int y = blockIdx.y;
  const int which = blockIdx.z & 1;
  const int b = blockIdx.z >> 1;
  const int rows = which ? 2048 : 1024;
  const int r0 = y * 256;
  float s = 0.f;
  if (r0 < rows) {
    const float* p = (which ? lang + (long)b * (2048L * 2048)
                            : vis + (long)b * (1024L * 2048)) + (long)r0 * H_ + h;
#pragma unroll 4
    for (int i = 0; i < 256; ++i) s += p[(long)i * H_];
  }
  part[(((long)which * 4 + b) * 8 + y) * H_ + h] = s;
}

__global__ __launch_bounds__(256) void col_sum_final(
    const float* __restrict__ part, float* __restrict__ vavg,
    float* __restrict__ lavg) {
  const int h = blockIdx.x * 256 + threadIdx.x;
  const int b = blockIdx.y;
  const int which = blockIdx.z;
  const float* p = part + (((long)which * 4 + b) * 8) * H_ + h;
  float s = 0.f;
#pragma unroll
  for (int y = 0; y < 8; ++y) s += p[y * H_];
  (which ? lavg : vavg)[b * H_ + h] = s * (1.f / 2048.f);
}

// ---------------------------------------------------------------------------
// bias GEMV: bias[b,h] = sum_{d<2048} avg[b,d] * W[h*4096 + d]
// ---------------------------------------------------------------------------
__global__ __launch_bounds__(256) void bias_gemv(
    const float* __restrict__ W, const float* __restrict__ avg,
    float* __restrict__ bias) {
  const int lane = threadIdx.x & 63;
  const int wv = threadIdx.x >> 6;
  const int h = blockIdx.x * 4 + wv;
  const float* wrow = W + (long)h * 4096;
  float a0 = 0.f, a1 = 0.f, a2 = 0.f, a3 = 0.f;
#pragma unroll
  for (int i = 0; i < 8; ++i) {
    const int d = i * 256 + lane * 4;
    f32x4 w4 = *(const f32x4*)(wrow + d);
    f32x4 v0 = *(const f32x4*)(avg + 0 * H_ + d);
    f32x4 v1 = *(const f32x4*)(avg + 1 * H_ + d);
    f32x4 v2 = *(const f32x4*)(avg + 2 * H_ + d);
    f32x4 v3 = *(const f32x4*)(avg + 3 * H_ + d);
    a0 += w4[0]*v0[0] + w4[1]*v0[1] + w4[2]*v0[2] + w4[3]*v0[3];
    a1 += w4[0]*v1[0] + w4[1]*v1[1] + w4[2]*v1[2] + w4[3]*v1[3];
    a2 += w4[0]*v2[0] + w4[1]*v2[1] + w4[2]*v2[2] + w4[3]*v2[3];
    a3 += w4[0]*v3[0] + w4[1]*v3[1] + w4[2]*v3[2] + w4[3]*v3[3];
  }
#pragma unroll
  for (int o = 32; o; o >>= 1) {
    a0 += __shfl_xor(a0, o, 64);
    a1 += __shfl_xor(a1, o, 64);
    a2 += __shfl_xor(a2, o, 64);
    a3 += __shfl_xor(a3, o, 64);
  }
  if (lane == 0) {
    bias[0 * H_ + h] = a0; bias[1 * H_ + h] = a1;
    bias[2 * H_ + h] = a2; bias[3 * H_ + h] = a3;
  }
}

// ---------------------------------------------------------------------------
// transpose lang (f32 [b][l][h]) -> lang_T (bf16 [b][h][l])
// ---------------------------------------------------------------------------
__global__ __launch_bounds__(256) void transpose_bf(
    const float* __restrict__ in, unsigned short* __restrict__ out) {
  __shared__ unsigned short tle[64][72];
  const int b = blockIdx.z;
  const int l0 = blockIdx.y * 64, h0 = blockIdx.x * 64;
  const float* inb = in + (long)b * (2048L * 2048);
  unsigned short* outb = out + (long)b * (2048L * 2048);
#pragma unroll
  for (int i = 0; i < 16; ++i) {
    const int idx = i * 256 + threadIdx.x;
    const int r = idx >> 6, c = idx & 63;
    tle[r][c] = f2bf(inb[(long)(l0 + r) * H_ + h0 + c]);
  }
  __syncthreads();
#pragma unroll
  for (int i = 0; i < 16; ++i) {
    const int idx = i * 256 + threadIdx.x;
    const int r = idx >> 6, c = idx & 63;  // r = h-local, c = l-local
    outb[(long)(h0 + r) * H_ + l0 + c] = tle[c][r];
  }
}

// ---------------------------------------------------------------------------
// extract W[:, 2048:4096] as bf16 row-major [h][k]
// ---------------------------------------------------------------------------
__global__ __launch_bounds__(256) void extract_whi(
    const float* __restrict__ Wvl, const float* __restrict__ Wlv,
    unsigned short* __restrict__ WvlHi, unsigned short* __restrict__ WlvHi) {
  const int h = blockIdx.x;
  const int which = blockIdx.y;
  const float* src = (which ? Wlv : Wvl) + (long)h * 4096 + 2048 + threadIdx.x * 8;
  unsigned short* dst = (which ? WlvHi : WvlHi) + (long)h * H_ + threadIdx.x * 8;
  f32x4 x0 = *(const f32x4*)src;
  f32x4 x1 = *(const f32x4*)(src + 4);
  u32x4 o;
  o[0] = pk2(x0[0], x0[1]); o[1] = pk2(x0[2], x0[3]);
  o[2] = pk2(x1[0], x1[1]); o[3] = pk2(x1[2], x1[3]);
  *(u32x4*)dst = o;
}

// ---------------------------------------------------------------------------
// row softmax in place over bf16 [rows][2048]
// ---------------------------------------------------------------------------
__global__ __launch_bounds__(256) void softmax_rows(unsigned short* __restrict__ S) {
  const int tid = threadIdx.x;
  const int lane = tid & 63, wv = tid >> 6;
  unsigned short* rowp = S + (long)blockIdx.x * H_ + tid * 8;
  u32x4 raw = *(const u32x4*)rowp;
  float v[8];
#pragma unroll
  for (int i = 0; i < 4; ++i) {
    v[2 * i]     = bf2f((unsigned short)(raw[i] & 0xFFFFu));
    v[2 * i + 1] = bf2f((unsigned short)(raw[i] >> 16));
  }
  float mx = v[0];
#pragma unroll
  for (int i = 1; i < 8; ++i) mx = fmaxf(mx, v[i]);
#pragma unroll
  for (int o = 32; o; o >>= 1) mx = fmaxf(mx, __shfl_xor(mx, o, 64));
  __shared__ float red[4];
  if (lane == 0) red[wv] = mx;
  __syncthreads();
  const float MX = fmaxf(fmaxf(red[0], red[1]), fmaxf(red[2], red[3]));
  float p[8], s = 0.f;
#pragma unroll
  for (int i = 0; i < 8; ++i) { p[i] = __expf(v[i] - MX); s += p[i]; }
#pragma unroll
  for (int o = 32; o; o >>= 1) s += __shfl_xor(s, o, 64);
  __syncthreads();
  if (lane == 0) red[wv] = s;
  __syncthreads();
  const float inv = 1.f / (red[0] + red[1] + red[2] + red[3]);
  u32x4 o;
#pragma unroll
  for (int i = 0; i < 4; ++i) o[i] = pk2(p[2 * i] * inv, p[2 * i + 1] * inv);
  *(u32x4*)rowp = o;
}

// ---------------------------------------------------------------------------
// NT GEMM (C = A * B^T), 256x256 tile, BK=32, 8 waves (2M x 4N).
// Decoupled-wave schedule: per K-tile, each wave does
//   [12x ds_read_b128 all fragments] lgkm(0)+schedbar  BAR1
//   STAGE(t+2)  vmcnt(4)  BAR2  [32x MFMA from regs]
// Only 2 barriers/K-tile; MFMA is register-only and overlaps other waves'
// LDS reads (m114 implicit wave overlap). Double-buffered 64KB LDS,
// conflict-free XOR swizzle kg^((lane>>1)&3) staged via inverse-swizzled
// global source (verified R2: 0 bank conflicts). XCD swizzle (T1).
// ---------------------------------------------------------------------------
struct EpArgs {
  unsigned short* Sout; const float* rv; const float* rl;  // MODE 0
  float* Fout;                                             // MODE 1
  const float* resid; const float* fusedIn; const float* bias; float* Oout;
  long sResid, sFused, sOut;                               // MODE 2
};

#define BAR_ asm volatile("s_barrier" ::: "memory")
#define WAITV_(n) asm volatile("s_waitcnt vmcnt(" #n ")" ::: "memory")
#define SYNCL_                                        \
  do {                                                \
    asm volatile("s_waitcnt lgkmcnt(0)" ::: "memory");\
    __builtin_amdgcn_sched_barrier(0);                \
  } while (0)

template <int MODE>
__global__ __launch_bounds__(512, 2) void gemm_nt(
    const unsigned short* __restrict__ A, long sA,
    const unsigned short* __restrict__ B, long sB, EpArgs ep) {
  // LDS (elements): A buf0 [0,8192) | A buf1 [8192,16384) | B buf0 | B buf1
  __shared__ unsigned short LDS[32768];  // 64 KB

  const int tid = threadIdx.x;
  const int lane = tid & 63;
  const int wave = tid >> 6;

  // XCD-aware bijective block swizzle (nwg % 8 == 0 for all our grids)
  const int gx = gridDim.x, gy = gridDim.y;
  const int nwg = gx * gy * gridDim.z;
  const int lin = blockIdx.x + gx * (blockIdx.y + gy * blockIdx.z);
  const int swz = (lin & 7) * (nwg >> 3) + (lin >> 3);
  const int bx = swz % gx;
  const int rest = swz / gx;
  const int by = rest % gy;
  const int b = rest / gy;
  const int bm = by << 8;
  const int bn = bx << 8;

  const unsigned short* Ab = A + (long)b * sA;
  const unsigned short* Bb = B + (long)b * sB;

  // --- staging addressing (global_load_lds: linear dest, pre-swz source) ---
  const int srow = tid >> 2;                              // 0..127
  const int colOff = (((tid & 3) ^ ((tid >> 3) & 3)) << 3);  // inv-swz k col
  const unsigned short* gA0 = Ab + (long)(bm + srow) * H_ + colOff;
  const unsigned short* gA1 = gA0 + 128 * H_;
  const unsigned short* gB0 = Bb + (long)(bn + srow) * H_ + colOff;
  const unsigned short* gB1 = gB0 + 128 * H_;
  const int ldst = wave * 512;  // wave-uniform LDS base (HW adds lane*16B)

  // parity p tile buffers (elements): A at p*8192, B at 16384 + p*8192
#define STAGE_(kt, P)                                             \
  do {                                                            \
    const unsigned short* pa0_ = gA0 + (kt) * 32;                 \
    const unsigned short* pa1_ = gA1 + (kt) * 32;                 \
    const unsigned short* pb0_ = gB0 + (kt) * 32;                 \
    const unsigned short* pb1_ = gB1 + (kt) * 32;                 \
    GLDS16(pa0_, &LDS[(P) * 8192 + ldst]);                        \
    GLDS16(pa1_, &LDS[(P) * 8192 + 4096 + ldst]);                 \
    GLDS16(pb0_, &LDS[16384 + (P) * 8192 + ldst]);                \
    GLDS16(pb1_, &LDS[16384 + (P) * 8192 + 4096 + ldst]);         \
  } while (0)

  // --- fragment addressing (swizzled read) ---
  const int row16 = lane & 15;
  const int kg = lane >> 4;
  const int kgs = kg ^ ((lane >> 1) & 3);  // conflict-free (R2-verified)
  const int wr = (wave >> 2) << 7;   // 0 or 128
  const int wc = (wave & 3) << 6;    // 0,64,128,192

  // byte-offset bases into LDS (AS3), one per operand x parity
  const unsigned baseA0 = (unsigned)(unsigned long long)(
      __attribute__((address_space(3))) const void*)
      &LDS[(wr + row16) * 32 + kgs * 8];
  const unsigned baseA1 = baseA0 + 16384u;
  const unsigned baseB0 = (unsigned)(unsigned long long)(
      __attribute__((address_space(3))) const void*)
      &LDS[16384 + (wc + row16) * 32 + kgs * 8];
  const unsigned baseB1 = baseB0 + 16384u;

#define DSR_(dst, base, off) \
  asm volatile("ds_read_b128 %0, %1 offset:" off : "=v"(dst) : "v"(base))

  f32x4 acc[8][4];
#pragma unroll
  for (int m = 0; m < 8; ++m)
#pragma unroll
    for (int n = 0; n < 4; ++n) acc[m][n] = (f32x4){0.f, 0.f, 0.f, 0.f};
  short8 aF[8], bF[4];

  // m stride = 16 rows * 32 el * 2B = 1024 bytes; n stride likewise
#define RDALL_(bA, bB)                         \
  do {                                         \
    DSR_(aF[0], bA, "0");                      \
    DSR_(aF[1], bA, "1024");                   \
    DSR_(aF[2], bA, "2048");                   \
    DSR_(aF[3], bA, "3072");                   \
    DSR_(aF[4], bA, "4096");                   \
    DSR_(aF[5], bA, "5120");                   \
    DSR_(aF[6], bA, "6144");                   \
    DSR_(aF[7], bA, "7168");                   \
    DSR_(bF[0], bB, "0");                      \
    DSR_(bF[1], bB, "1024");                   \
    DSR_(bF[2], bB, "2048");                   \
    DSR_(bF[3], bB, "3072");                   \
  } while (0)

#define MFMA32_                                                             \
  do {                                                                      \
    __builtin_amdgcn_s_setprio(1);                                          \
    _Pragma("unroll") for (int m_ = 0; m_ < 8; ++m_)                        \
    _Pragma("unroll") for (int n_ = 0; n_ < 4; ++n_)                        \
        acc[m_][n_] = __builtin_amdgcn_mfma_f32_16x16x32_bf16(              \
            aF[m_], bF[n_], acc[m_][n_], 0, 0, 0);                          \
    __builtin_amdgcn_s_setprio(0);                                          \
  } while (0)

  // prologue: stage tiles 0,1; wait tile0 landed (4 newest = tile1); publish
  STAGE_(0, 0); STAGE_(1, 1);
  WAITV_(4);
  BAR_;

  // steady state: t = 0..61 (stage t+2), even/odd unrolled for literal bases
  for (int tt = 0; tt < 31; ++tt) {
    const int t2 = tt * 2;
    RDALL_(baseA0, baseB0); SYNCL_;
    BAR_;                       // all waves' reads of tile t2 done (WAR)
    STAGE_(t2 + 2, 0);          // same parity as t2
    WAITV_(4);                  // tile t2+1 landed
    BAR_;                       // publish t2+1
    MFMA32_;
    RDALL_(baseA1, baseB1); SYNCL_;
    BAR_;
    STAGE_(t2 + 3, 1);
    WAITV_(4);
    BAR_;
    MFMA32_;
  }
  // t = 62 (parity 0): no stage; drain to publish tile 63
  RDALL_(baseA0, baseB0); SYNCL_;
  BAR_;
  WAITV_(0);
  BAR_;
  MFMA32_;
  // t = 63 (parity 1)
  RDALL_(baseA1, baseB1); SYNCL_;
  MFMA32_;

  // C/D layout: col = lane&15, row = (lane>>4)*4 + j   [verified m89/m91]
  const int cr0 = bm + wr + kg * 4;
  const int cc0 = bn + wc + row16;

  if (MODE == 0) {
    float rvv[8][4], rlv[4];
#pragma unroll
    for (int m = 0; m < 8; ++m)
#pragma unroll
      for (int j = 0; j < 4; ++j) rvv[m][j] = ep.rv[b * H_ + cr0 + m * 16 + j];
#pragma unroll
    for (int n = 0; n < 4; ++n) rlv[n] = ep.rl[b * H_ + cc0 + n * 16];
    unsigned short* Sb = ep.Sout + (long)b * (H_ * (long)H_);
#pragma unroll
    for (int m = 0; m < 8; ++m)
#pragma unroll
      for (int n = 0; n < 4; ++n)
#pragma unroll
        for (int j = 0; j < 4; ++j) {
          const long idx = (long)(cr0 + m * 16 + j) * H_ + cc0 + n * 16;
          Sb[idx] = f2bf(acc[m][n][j] * rvv[m][j] * rlv[n]);
        }
  } else if (MODE == 1) {
    float* Fb = ep.Fout + (long)b * (H_ * (long)H_);
#pragma unroll
    for (int m = 0; m < 8; ++m)
#pragma unroll
      for (int n = 0; n < 4; ++n)
#pragma unroll
        for (int j = 0; j < 4; ++j) {
          const long idx = (long)(cr0 + m * 16 + j) * H_ + cc0 + n * 16;
          Fb[idx] = acc[m][n][j];
        }
  } else {
    const float* Rb = ep.resid + (long)b * ep.sResid;
    const float* Fb = ep.fusedIn + (long)b * ep.sFused;
    float* Ob = ep.Oout + (long)b * ep.sOut;
    float bv[4];
#pragma unroll
    for (int n = 0; n < 4; ++n) bv[n] = ep.bias[b * H_ + cc0 + n * 16];
#pragma unroll
    for (int m = 0; m < 8; ++m)
#pragma unroll
      for (int n = 0; n < 4; ++n)
#pragma unroll
        for (int j = 0; j < 4; ++j) {
          const long idx = (long)(cr0 + m * 16 + j) * H_ + cc0 + n * 16;
          const float x = acc[m][n][j] + bv[n];
          const float g = 1.f / (1.f + __expf(-x));
          Ob[idx] = Rb[idx] + Fb[idx] * g;
        }
  }
#undef STAGE_
#undef DSR_
#undef RDALL_
#undef MFMA32_
}

// ---------------------------------------------------------------------------
extern "C" void kernel_launch(void* const* d_in, const int* in_sizes, int n_in,
                              void* d_out, int out_size, void* d_ws,
                              size_t ws_size, hipStream_t stream) {
  (void)in_sizes; (void)n_in; (void)out_size; (void)ws_size;
  const float* vis = (const float*)d_in[0];   // [4,1024,2048]
  const float* lang = (const float*)d_in[1];  // [4,2048,2048]
  const float* Wvl = (const float*)d_in[2];   // [2048,4096]
  const float* Wlv = (const float*)d_in[3];   // [2048,4096]

  // d_out regions: fused | vision_output | language_output
  float* out = (float*)d_out;
  float* fused = out;                      // 16,777,216 f32
  float* vis_out = out + 16777216;         //  8,388,608 f32
  float* lang_out = out + 25165824;        // 16,777,216 f32
  // scratch reuse of not-yet-final output regions:
  unsigned short* S = (unsigned short*)lang_out;     // scores/P bf16
  unsigned short* langT = (unsigned short*)vis_out;  // lang^T bf16

  // workspace layout
  char* w = (char*)d_ws;
  unsigned short* vis_bf = (unsigned short*)w;               // [4,2048,2048] bf16 (padded)
  unsigned short* lang_bf = (unsigned short*)(w + 33554432); // [4,2048,2048] bf16
  unsigned short* WvlHi = (unsigned short*)(w + 67108864);   // [2048,2048] bf16
  unsigned short* WlvHi = (unsigned short*)(w + 75497472);   // [2048,2048] bf16
  float* rv      = (float*)(w + 83886080);
  float* rl      = (float*)(w + 83918848);
  float* vavg    = (float*)(w + 83951616);
  float* lavg    = (float*)(w + 83984384);
  float* bias_vl = (float*)(w + 84017152);
  float* bias_lv = (float*)(w + 84049920);
  float* part    = (float*)(w + 84082688);  // 512KB partial col sums

  const long sV = 1024L * 2048, sL = 2048L * 2048, sP = 2048L * 2048;

  prep_rows<<<dim3(2048, 4), 256, 0, stream>>>(vis, sV, vis_bf, sP, rv, 1024);
  prep_rows<<<dim3(2048, 4), 256, 0, stream>>>(lang, sL, lang_bf, sP, rl, 2048);
  col_sum_part<<<dim3(8, 8, 8), 256, 0, stream>>>(vis, lang, part);
  col_sum_final<<<dim3(8, 4, 2), 256, 0, stream>>>(part, vavg, lavg);
  bias_gemv<<<512, 256, 0, stream>>>(Wvl, vavg, bias_vl);
  bias_gemv<<<512, 256, 0, stream>>>(Wlv, lavg, bias_lv);
  transpose_bf<<<dim3(32, 32, 4), 256, 0, stream>>>(lang, langT);
  extract_whi<<<dim3(2048, 2), 256, 0, stream>>>(Wvl, Wlv, WvlHi, WlvHi);

  // GEMM1: scores S[b,v,l] = (vis . lang) * rv * rl  -> bf16
  EpArgs e1 = {};
  e1.Sout = S; e1.rv = rv; e1.rl = rl;
  gemm_nt<0><<<dim3(8, 8, 4), 512, 0, stream>>>(vis_bf, sP, lang_bf, sP, e1);

  softmax_rows<<<8192, 256, 0, stream>>>(S);

  // GEMM2: fused[b,v,h] = P . lang  (B = lang^T, NT form) -> f32
  EpArgs e2 = {};
  e2.Fout = fused;
  gemm_nt<1><<<dim3(8, 8, 4), 512, 0, stream>>>(S, sP, langT, sP, e2);

  // GEMM3: language_output = lang + fused * sigmoid(lang.WvlHi^T + bias_vl)
  EpArgs e3 = {};
  e3.resid = lang; e3.sResid = sL;
  e3.fusedIn = fused; e3.sFused = sP;
  e3.bias = bias_vl; e3.Oout = lang_out; e3.sOut = sL;
  gemm_nt<2><<<dim3(8, 8, 4), 512, 0, stream>>>(lang_bf, sP, WvlHi, 0L, e3);

  // GEMM4: vision_output = vis + fused[:, :1024] * sigmoid(vis.WlvHi^T + bias_lv)
  EpArgs e4 = {};
  e4.resid = vis; e4.sResid = sV;
  e4.fusedIn = fused; e4.sFused = sP;
  e4.bias = bias_lv; e4.Oout = vis_out; e4.sOut = sV;
  gemm_nt<2><<<dim3(8, 4, 4), 512, 0, stream>>>(vis_bf, sP, WlvHi, 0L, e4);
}

// Round 6
// 487.318 us; speedup vs baseline: 1.0506x; 1.0468x over previous
//
#include <hip/hip_runtime.h>

// Problem constants (B=4, V=1024, L=2048, H=2048, TEMP=1, EPS=1e-12)
#define H_ 2048

typedef __attribute__((ext_vector_type(8))) short short8;
typedef __attribute__((ext_vector_type(4))) float f32x4;
typedef __attribute__((ext_vector_type(4))) unsigned int u32x4;

__device__ __forceinline__ unsigned short f2bf(float f) {
  unsigned int u = __builtin_bit_cast(unsigned int, f);
  u += 0x7FFFu + ((u >> 16) & 1u);  // RTNE
  return (unsigned short)(u >> 16);
}
__device__ __forceinline__ float bf2f(unsigned short h) {
  unsigned int u = ((unsigned int)h) << 16;
  return __builtin_bit_cast(float, u);
}
__device__ __forceinline__ unsigned int pk2(float a, float b) {
  return (unsigned int)f2bf(a) | ((unsigned int)f2bf(b) << 16);
}

#define GLDS16(gp, lp)                                                 \
  __builtin_amdgcn_global_load_lds(                                    \
      (const __attribute__((address_space(1))) void*)(gp),             \
      (__attribute__((address_space(3))) void*)(lp), 16, 0, 0)

// ---------------------------------------------------------------------------
// prep: per-row 1/max(||row||,eps) + raw bf16 copy; rows >= validRows -> zeros
// ---------------------------------------------------------------------------
__global__ __launch_bounds__(256) void prep_rows(
    const float* __restrict__ in, long sIn,
    unsigned short* __restrict__ outBf, long sOut,
    float* __restrict__ rnorm, int validRows) {
  const int tid = threadIdx.x;
  const int r = blockIdx.x, b = blockIdx.y;
  unsigned short* orow = outBf + (long)b * sOut + (long)r * H_ + tid * 8;
  if (r >= validRows) {
    *(u32x4*)orow = (u32x4){0u, 0u, 0u, 0u};
    if (tid == 0) rnorm[b * H_ + r] = 0.f;
    return;
  }
  const float* row = in + (long)b * sIn + (long)r * H_ + tid * 8;
  f32x4 x0 = *(const f32x4*)row;
  f32x4 x1 = *(const f32x4*)(row + 4);
  float ss = x0[0]*x0[0] + x0[1]*x0[1] + x0[2]*x0[2] + x0[3]*x0[3]
           + x1[0]*x1[0] + x1[1]*x1[1] + x1[2]*x1[2] + x1[3]*x1[3];
#pragma unroll
  for (int o = 32; o; o >>= 1) ss += __shfl_xor(ss, o, 64);
  __shared__ float red[4];
  if ((tid & 63) == 0) red[tid >> 6] = ss;
  __syncthreads();
  if (tid == 0) {
    float tot = red[0] + red[1] + red[2] + red[3];
    rnorm[b * H_ + r] = 1.f / fmaxf(sqrtf(tot), 1e-12f);
  }
  u32x4 o;
  o[0] = pk2(x0[0], x0[1]); o[1] = pk2(x0[2], x0[3]);
  o[2] = pk2(x1[0], x1[1]); o[3] = pk2(x1[2], x1[3]);
  *(u32x4*)orow = o;
}

// ---------------------------------------------------------------------------
// column sums (means over padded length 2048) — two stage for parallelism
// ---------------------------------------------------------------------------
__global__ __launch_bounds__(256) void col_sum_part(
    const float* __restrict__ vis, const float* __restrict__ lang,
    float* __restrict__ part) {
  const int h = blockIdx.x * 256 + threadIdx.x;
  const int y = blockIdx.y;
  const int which = blockIdx.z & 1;
  const int b = blockIdx.z >> 1;
  const int rows = which ? 2048 : 1024;
  const int r0 = y * 256;
  float s = 0.f;
  if (r0 < rows) {
    const float* p = (which ? lang + (long)b * (2048L * 2048)
                            : vis + (long)b * (1024L * 2048)) + (long)r0 * H_ + h;
#pragma unroll 4
    for (int i = 0; i < 256; ++i) s += p[(long)i * H_];
  }
  part[(((long)which * 4 + b) * 8 + y) * H_ + h] = s;
}

__global__ __launch_bounds__(256) void col_sum_final(
    const float* __restrict__ part, float* __restrict__ vavg,
    float* __restrict__ lavg) {
  const int h = blockIdx.x * 256 + threadIdx.x;
  const int b = blockIdx.y;
  const int which = blockIdx.z;
  const float* p = part + (((long)which * 4 + b) * 8) * H_ + h;
  float s = 0.f;
#pragma unroll
  for (int y = 0; y < 8; ++y) s += p[y * H_];
  (which ? lavg : vavg)[b * H_ + h] = s * (1.f / 2048.f);
}

// ---------------------------------------------------------------------------
// bias GEMV: bias[b,h] = sum_{d<2048} avg[b,d] * W[h*4096 + d]
// ---------------------------------------------------------------------------
__global__ __launch_bounds__(256) void bias_gemv(
    const float* __restrict__ W, const float* __restrict__ avg,
    float* __restrict__ bias) {
  const int lane = threadIdx.x & 63;
  const int wv = threadIdx.x >> 6;
  const int h = blockIdx.x * 4 + wv;
  const float* wrow = W + (long)h * 4096;
  float a0 = 0.f, a1 = 0.f, a2 = 0.f, a3 = 0.f;
#pragma unroll
  for (int i = 0; i < 8; ++i) {
    const int d = i * 256 + lane * 4;
    f32x4 w4 = *(const f32x4*)(wrow + d);
    f32x4 v0 = *(const f32x4*)(avg + 0 * H_ + d);
    f32x4 v1 = *(const f32x4*)(avg + 1 * H_ + d);
    f32x4 v2 = *(const f32x4*)(avg + 2 * H_ + d);
    f32x4 v3 = *(const f32x4*)(avg + 3 * H_ + d);
    a0 += w4[0]*v0[0] + w4[1]*v0[1] + w4[2]*v0[2] + w4[3]*v0[3];
    a1 += w4[0]*v1[0] + w4[1]*v1[1] + w4[2]*v1[2] + w4[3]*v1[3];
    a2 += w4[0]*v2[0] + w4[1]*v2[1] + w4[2]*v2[2] + w4[3]*v2[3];
    a3 += w4[0]*v3[0] + w4[1]*v3[1] + w4[2]*v3[2] + w4[3]*v3[3];
  }
#pragma unroll
  for (int o = 32; o; o >>= 1) {
    a0 += __shfl_xor(a0, o, 64);
    a1 += __shfl_xor(a1, o, 64);
    a2 += __shfl_xor(a2, o, 64);
    a3 += __shfl_xor(a3, o, 64);
  }
  if (lane == 0) {
    bias[0 * H_ + h] = a0; bias[1 * H_ + h] = a1;
    bias[2 * H_ + h] = a2; bias[3 * H_ + h] = a3;
  }
}

// ---------------------------------------------------------------------------
// transpose lang (f32 [b][l][h]) -> lang_T (bf16 [b][h][l])
// ---------------------------------------------------------------------------
__global__ __launch_bounds__(256) void transpose_bf(
    const float* __restrict__ in, unsigned short* __restrict__ out) {
  __shared__ unsigned short tle[64][72];
  const int b = blockIdx.z;
  const int l0 = blockIdx.y * 64, h0 = blockIdx.x * 64;
  const float* inb = in + (long)b * (2048L * 2048);
  unsigned short* outb = out + (long)b * (2048L * 2048);
#pragma unroll
  for (int i = 0; i < 16; ++i) {
    const int idx = i * 256 + threadIdx.x;
    const int r = idx >> 6, c = idx & 63;
    tle[r][c] = f2bf(inb[(long)(l0 + r) * H_ + h0 + c]);
  }
  __syncthreads();
#pragma unroll
  for (int i = 0; i < 16; ++i) {
    const int idx = i * 256 + threadIdx.x;
    const int r = idx >> 6, c = idx & 63;  // r = h-local, c = l-local
    outb[(long)(h0 + r) * H_ + l0 + c] = tle[c][r];
  }
}

// ---------------------------------------------------------------------------
// extract W[:, 2048:4096] as bf16 row-major [h][k]
// ---------------------------------------------------------------------------
__global__ __launch_bounds__(256) void extract_whi(
    const float* __restrict__ Wvl, const float* __restrict__ Wlv,
    unsigned short* __restrict__ WvlHi, unsigned short* __restrict__ WlvHi) {
  const int h = blockIdx.x;
  const int which = blockIdx.y;
  const float* src = (which ? Wlv : Wvl) + (long)h * 4096 + 2048 + threadIdx.x * 8;
  unsigned short* dst = (which ? WlvHi : WvlHi) + (long)h * H_ + threadIdx.x * 8;
  f32x4 x0 = *(const f32x4*)src;
  f32x4 x1 = *(const f32x4*)(src + 4);
  u32x4 o;
  o[0] = pk2(x0[0], x0[1]); o[1] = pk2(x0[2], x0[3]);
  o[2] = pk2(x1[0], x1[1]); o[3] = pk2(x1[2], x1[3]);
  *(u32x4*)dst = o;
}

// ---------------------------------------------------------------------------
// row softmax in place over bf16 [rows][2048]
// ---------------------------------------------------------------------------
__global__ __launch_bounds__(256) void softmax_rows(unsigned short* __restrict__ S) {
  const int tid = threadIdx.x;
  const int lane = tid & 63, wv = tid >> 6;
  unsigned short* rowp = S + (long)blockIdx.x * H_ + tid * 8;
  u32x4 raw = *(const u32x4*)rowp;
  float v[8];
#pragma unroll
  for (int i = 0; i < 4; ++i) {
    v[2 * i]     = bf2f((unsigned short)(raw[i] & 0xFFFFu));
    v[2 * i + 1] = bf2f((unsigned short)(raw[i] >> 16));
  }
  float mx = v[0];
#pragma unroll
  for (int i = 1; i < 8; ++i) mx = fmaxf(mx, v[i]);
#pragma unroll
  for (int o = 32; o; o >>= 1) mx = fmaxf(mx, __shfl_xor(mx, o, 64));
  __shared__ float red[4];
  if (lane == 0) red[wv] = mx;
  __syncthreads();
  const float MX = fmaxf(fmaxf(red[0], red[1]), fmaxf(red[2], red[3]));
  float p[8], s = 0.f;
#pragma unroll
  for (int i = 0; i < 8; ++i) { p[i] = __expf(v[i] - MX); s += p[i]; }
#pragma unroll
  for (int o = 32; o; o >>= 1) s += __shfl_xor(s, o, 64);
  __syncthreads();
  if (lane == 0) red[wv] = s;
  __syncthreads();
  const float inv = 1.f / (red[0] + red[1] + red[2] + red[3]);
  u32x4 o;
#pragma unroll
  for (int i = 0; i < 4; ++i) o[i] = pk2(p[2 * i] * inv, p[2 * i + 1] * inv);
  *(u32x4*)rowp = o;
}

// ---------------------------------------------------------------------------
// NT GEMM (C = A * B^T), 256x256 tile, BK=32, 8 waves (2M x 4N).
// Wave-internal software pipeline: tile t's 32 MFMAs are INTERLEAVED with
// tile t+1's 12 ds_read_b128 (sched_barrier-pinned groups); each read
// overwrites a fragment register right after its last MFMA consumer (WAR-safe:
// MFMA latches sources at issue) -> zero extra registers. 3-deep LDS
// buffering (96KB): stage t+3, vmcnt(4) lands t+2, barrier publishes.
// Conflict-free XOR swizzle kg^((lane>>1)&3) via inverse-swizzled global
// source (R2-verified: 0 bank conflicts). XCD swizzle (T1).
// ---------------------------------------------------------------------------
struct EpArgs {
  unsigned short* Sout; const float* rv; const float* rl;  // MODE 0
  float* Fout;                                             // MODE 1
  const float* resid; const float* fusedIn; const float* bias; float* Oout;
  long sResid, sFused, sOut;                               // MODE 2
};

#define BAR_ asm volatile("s_barrier" ::: "memory")
#define WAITV_(n) asm volatile("s_waitcnt vmcnt(" #n ")" ::: "memory")
#define LGKM0_ asm volatile("s_waitcnt lgkmcnt(0)" ::: "memory")
#define SB_ __builtin_amdgcn_sched_barrier(0)

template <int MODE>
__global__ __launch_bounds__(512, 2) void gemm_nt(
    const unsigned short* __restrict__ A, long sA,
    const unsigned short* __restrict__ B, long sB, EpArgs ep) {
  // LDS: 3 buffers x 32KB; buffer j: A[256][32] at j*16384, B at j*16384+8192
  __shared__ unsigned short LDS[49152];  // 96 KB

  const int tid = threadIdx.x;
  const int lane = tid & 63;
  const int wave = tid >> 6;

  // XCD-aware bijective block swizzle (nwg % 8 == 0 for all our grids)
  const int gx = gridDim.x, gy = gridDim.y;
  const int nwg = gx * gy * gridDim.z;
  const int lin = blockIdx.x + gx * (blockIdx.y + gy * blockIdx.z);
  const int swz = (lin & 7) * (nwg >> 3) + (lin >> 3);
  const int bx = swz % gx;
  const int rest = swz / gx;
  const int by = rest % gy;
  const int b = rest / gy;
  const int bm = by << 8;
  const int bn = bx << 8;

  const unsigned short* Ab = A + (long)b * sA;
  const unsigned short* Bb = B + (long)b * sB;

  // --- staging addressing (global_load_lds: linear dest, pre-swz source) ---
  const int srow = tid >> 2;                                 // 0..127
  const int colOff = (((tid & 3) ^ ((tid >> 3) & 3)) << 3);  // inv-swz k col
  const unsigned short* sA0 = Ab + (long)(bm + srow) * H_ + colOff;
  const unsigned short* sA1 = sA0 + 128 * H_;
  const unsigned short* sB0 = Bb + (long)(bn + srow) * H_ + colOff;
  const unsigned short* sB1 = sB0 + 128 * H_;
  const int ldst = wave * 512;  // wave-uniform LDS base (HW adds lane*16B)

#define STAGE_J(J, KO)                                        \
  do {                                                        \
    GLDS16(sA0 + (KO) * 32, &LDS[(J) * 16384 + ldst]);        \
    GLDS16(sA1 + (KO) * 32, &LDS[(J) * 16384 + 4096 + ldst]); \
    GLDS16(sB0 + (KO) * 32, &LDS[(J) * 16384 + 8192 + ldst]); \
    GLDS16(sB1 + (KO) * 32, &LDS[(J) * 16384 + 12288 + ldst]);\
  } while (0)

  // --- fragment addressing (swizzled read) ---
  const int row16 = lane & 15;
  const int kg = lane >> 4;
  const int kgs = kg ^ ((lane >> 1) & 3);  // conflict-free (R2-verified)
  const int wr = (wave >> 2) << 7;   // 0 or 128
  const int wc = (wave & 3) << 6;    // 0,64,128,192

  const unsigned baseAb = (unsigned)(unsigned long long)(
      __attribute__((address_space(3))) const void*)
      &LDS[(wr + row16) * 32 + kgs * 8];
  const unsigned baseBb = (unsigned)(unsigned long long)(
      __attribute__((address_space(3))) const void*)
      &LDS[8192 + (wc + row16) * 32 + kgs * 8];
  const unsigned bA0 = baseAb, bA1 = baseAb + 32768u, bA2 = baseAb + 65536u;
  const unsigned bB0 = baseBb, bB1 = baseBb + 32768u, bB2 = baseBb + 65536u;

#define DSRD_(dst, base, off) \
  asm volatile("ds_read_b128 %0, %1 offset:" #off : "=v"(dst) : "v"(base))

  f32x4 acc[8][4];
#pragma unroll
  for (int m = 0; m < 8; ++m)
#pragma unroll
    for (int n = 0; n < 4; ++n) acc[m][n] = (f32x4){0.f, 0.f, 0.f, 0.f};
  short8 aF[8], bF[4];

#define MM1_(m, n)                                              \
  acc[m][n] = __builtin_amdgcn_mfma_f32_16x16x32_bf16(          \
      aF[m], bF[n], acc[m][n], 0, 0, 0)
#define MG_(m) do { MM1_(m, 0); MM1_(m, 1); MM1_(m, 2); MM1_(m, 3); } while (0)
#define MP_(n) do { MM1_(6, n); MM1_(7, n); } while (0)
#define MALL_                                                   \
  do { MG_(0); MG_(1); MG_(2); MG_(3); MG_(4); MG_(5);          \
       MP_(0); MP_(1); MP_(2); MP_(3); } while (0)

  // Interleave: MFMAs of current tile + ds_reads of next tile into the SAME
  // fragment registers, each read placed after its register's last consumer.
#define ILV_(bA, bB)                                            \
  do {                                                          \
    MG_(0); SB_;                                                \
    MG_(1); SB_;                                                \
    DSRD_(aF[0], bA, 0);    MG_(2); SB_;                        \
    DSRD_(aF[1], bA, 1024); MG_(3); SB_;                        \
    DSRD_(aF[2], bA, 2048); MG_(4); SB_;                        \
    DSRD_(aF[3], bA, 3072); MG_(5); SB_;                        \
    DSRD_(aF[4], bA, 4096); MP_(0); SB_;                        \
    DSRD_(aF[5], bA, 5120); DSRD_(bF[0], bB, 0); MP_(1); SB_;   \
    DSRD_(bF[1], bB, 1024); MP_(2); SB_;                        \
    DSRD_(bF[2], bB, 2048); MP_(3); SB_;                        \
    DSRD_(bF[3], bB, 3072); DSRD_(aF[6], bA, 6144);             \
    DSRD_(aF[7], bA, 7168); SB_;                                \
  } while (0)

#define RDALL0_                                                 \
  do {                                                          \
    DSRD_(aF[0], bA0, 0);    DSRD_(aF[1], bA0, 1024);           \
    DSRD_(aF[2], bA0, 2048); DSRD_(aF[3], bA0, 3072);           \
    DSRD_(aF[4], bA0, 4096); DSRD_(aF[5], bA0, 5120);           \
    DSRD_(aF[6], bA0, 6144); DSRD_(aF[7], bA0, 7168);           \
    DSRD_(bF[0], bB0, 0);    DSRD_(bF[1], bB0, 1024);           \
    DSRD_(bF[2], bB0, 2048); DSRD_(bF[3], bB0, 3072);           \
  } while (0)

  // prologue: stage tiles 0,1,2 (12 loads); t0 lands; read t0; t1 lands.
  STAGE_J(0, 0); STAGE_J(1, 1); STAGE_J(2, 2);
  sA0 += 96; sA1 += 96; sB0 += 96; sB1 += 96;
  WAITV_(8);
  BAR_;
  RDALL0_; LGKM0_; SB_;
  WAITV_(4);
  BAR_;

  // steady state t = 0..59 (stage t+3; KO 0/1/2 from advancing base kt=3*i+3)
  for (int i = 0; i < 20; ++i) {
    // t = 3i: reads t+1 (buf1), stages t+3 -> buf0
    ILV_(bA1, bB1); LGKM0_; SB_;
    BAR_; STAGE_J(0, 0); WAITV_(4); BAR_;
    // t = 3i+1: reads (buf2), stage -> buf1
    ILV_(bA2, bB2); LGKM0_; SB_;
    BAR_; STAGE_J(1, 1); WAITV_(4); BAR_;
    // t = 3i+2: reads (buf0), stage -> buf2
    ILV_(bA0, bB0); LGKM0_; SB_;
    BAR_; STAGE_J(2, 2); WAITV_(4); BAR_;
    sA0 += 96; sA1 += 96; sB0 += 96; sB1 += 96;
  }
  // t = 60: reads t61 (buf1), stages kt=63 -> buf0
  ILV_(bA1, bB1); LGKM0_; SB_;
  BAR_; STAGE_J(0, 0); WAITV_(4); BAR_;
  // t = 61: reads t62 (buf2); drain t63
  ILV_(bA2, bB2); LGKM0_; SB_;
  BAR_; WAITV_(0); BAR_;
  // t = 62: reads t63 (buf0)
  ILV_(bA0, bB0); LGKM0_; SB_;
  // t = 63: MFMA only
  MALL_;

  // C/D layout: col = lane&15, row = (lane>>4)*4 + j   [verified m89/m91]
  const int cr0 = bm + wr + kg * 4;
  const int cc0 = bn + wc + row16;

  if (MODE == 0) {
    float rvv[8][4], rlv[4];
#pragma unroll
    for (int m = 0; m < 8; ++m)
#pragma unroll
      for (int j = 0; j < 4; ++j) rvv[m][j] = ep.rv[b * H_ + cr0 + m * 16 + j];
#pragma unroll
    for (int n = 0; n < 4; ++n) rlv[n] = ep.rl[b * H_ + cc0 + n * 16];
    unsigned short* Sb = ep.Sout + (long)b * (H_ * (long)H_);
#pragma unroll
    for (int m = 0; m < 8; ++m)
#pragma unroll
      for (int n = 0; n < 4; ++n)
#pragma unroll
        for (int j = 0; j < 4; ++j) {
          const long idx = (long)(cr0 + m * 16 + j) * H_ + cc0 + n * 16;
          Sb[idx] = f2bf(acc[m][n][j] * rvv[m][j] * rlv[n]);
        }
  } else if (MODE == 1) {
    float* Fb = ep.Fout + (long)b * (H_ * (long)H_);
#pragma unroll
    for (int m = 0; m < 8; ++m)
#pragma unroll
      for (int n = 0; n < 4; ++n)
#pragma unroll
        for (int j = 0; j < 4; ++j) {
          const long idx = (long)(cr0 + m * 16 + j) * H_ + cc0 + n * 16;
          Fb[idx] = acc[m][n][j];
        }
  } else {
    const float* Rb = ep.resid + (long)b * ep.sResid;
    const float* Fb = ep.fusedIn + (long)b * ep.sFused;
    float* Ob = ep.Oout + (long)b * ep.sOut;
    float bv[4];
#pragma unroll
    for (int n = 0; n < 4; ++n) bv[n] = ep.bias[b * H_ + cc0 + n * 16];
#pragma unroll
    for (int m = 0; m < 8; ++m)
#pragma unroll
      for (int n = 0; n < 4; ++n)
#pragma unroll
        for (int j = 0; j < 4; ++j) {
          const long idx = (long)(cr0 + m * 16 + j) * H_ + cc0 + n * 16;
          const float x = acc[m][n][j] + bv[n];
          const float g = 1.f / (1.f + __expf(-x));
          Ob[idx] = Rb[idx] + Fb[idx] * g;
        }
  }
#undef STAGE_J
#undef DSRD_
#undef MM1_
#undef MG_
#undef MP_
#undef MALL_
#undef ILV_
#undef RDALL0_
}

// ---------------------------------------------------------------------------
extern "C" void kernel_launch(void* const* d_in, const int* in_sizes, int n_in,
                              void* d_out, int out_size, void* d_ws,
                              size_t ws_size, hipStream_t stream) {
  (void)in_sizes; (void)n_in; (void)out_size; (void)ws_size;
  const float* vis = (const float*)d_in[0];   // [4,1024,2048]
  const float* lang = (const float*)d_in[1];  // [4,2048,2048]
  const float* Wvl = (const float*)d_in[2];   // [2048,4096]
  const float* Wlv = (const float*)d_in[3];   // [2048,4096]

  // d_out regions: fused | vision_output | language_output
  float* out = (float*)d_out;
  float* fused = out;                      // 16,777,216 f32
  float* vis_out = out + 16777216;         //  8,388,608 f32
  float* lang_out = out + 25165824;        // 16,777,216 f32
  // scratch reuse of not-yet-final output regions:
  unsigned short* S = (unsigned short*)lang_out;     // scores/P bf16
  unsigned short* langT = (unsigned short*)vis_out;  // lang^T bf16

  // workspace layout
  char* w = (char*)d_ws;
  unsigned short* vis_bf = (unsigned short*)w;               // [4,2048,2048] bf16 (padded)
  unsigned short* lang_bf = (unsigned short*)(w + 33554432); // [4,2048,2048] bf16
  unsigned short* WvlHi = (unsigned short*)(w + 67108864);   // [2048,2048] bf16
  unsigned short* WlvHi = (unsigned short*)(w + 75497472);   // [2048,2048] bf16
  float* rv      = (float*)(w + 83886080);
  float* rl      = (float*)(w + 83918848);
  float* vavg    = (float*)(w + 83951616);
  float* lavg    = (float*)(w + 83984384);
  float* bias_vl = (float*)(w + 84017152);
  float* bias_lv = (float*)(w + 84049920);
  float* part    = (float*)(w + 84082688);  // 512KB partial col sums

  const long sV = 1024L * 2048, sL = 2048L * 2048, sP = 2048L * 2048;

  prep_rows<<<dim3(2048, 4), 256, 0, stream>>>(vis, sV, vis_bf, sP, rv, 1024);
  prep_rows<<<dim3(2048, 4), 256, 0, stream>>>(lang, sL, lang_bf, sP, rl, 2048);
  col_sum_part<<<dim3(8, 8, 8), 256, 0, stream>>>(vis, lang, part);
  col_sum_final<<<dim3(8, 4, 2), 256, 0, stream>>>(part, vavg, lavg);
  bias_gemv<<<512, 256, 0, stream>>>(Wvl, vavg, bias_vl);
  bias_gemv<<<512, 256, 0, stream>>>(Wlv, lavg, bias_lv);
  transpose_bf<<<dim3(32, 32, 4), 256, 0, stream>>>(lang, langT);
  extract_whi<<<dim3(2048, 2), 256, 0, stream>>>(Wvl, Wlv, WvlHi, WlvHi);

  // GEMM1: scores S[b,v,l] = (vis . lang) * rv * rl  -> bf16
  EpArgs e1 = {};
  e1.Sout = S; e1.rv = rv; e1.rl = rl;
  gemm_nt<0><<<dim3(8, 8, 4), 512, 0, stream>>>(vis_bf, sP, lang_bf, sP, e1);

  softmax_rows<<<8192, 256, 0, stream>>>(S);

  // GEMM2: fused[b,v,h] = P . lang  (B = lang^T, NT form) -> f32
  EpArgs e2 = {};
  e2.Fout = fused;
  gemm_nt<1><<<dim3(8, 8, 4), 512, 0, stream>>>(S, sP, langT, sP, e2);

  // GEMM3: language_output = lang + fused * sigmoid(lang.WvlHi^T + bias_vl)
  EpArgs e3 = {};
  e3.resid = lang; e3.sResid = sL;
  e3.fusedIn = fused; e3.sFused = sP;
  e3.bias = bias_vl; e3.Oout = lang_out; e3.sOut = sL;
  gemm_nt<2><<<dim3(8, 8, 4), 512, 0, stream>>>(lang_bf, sP, WvlHi, 0L, e3);

  // GEMM4: vision_output = vis + fused[:, :1024] * sigmoid(vis.WlvHi^T + bias_lv)
  EpArgs e4 = {};
  e4.resid = vis; e4.sResid = sV;
  e4.fusedIn = fused; e4.sFused = sP;
  e4.bias = bias_lv; e4.Oout = vis_out; e4.sOut = sV;
  gemm_nt<2><<<dim3(8, 4, 4), 512, 0, stream>>>(vis_bf, sP, WlvHi, 0L, e4);
}